// Round 1
// baseline (1777.761 us; speedup 1.0000x reference)
//
#include <hip/hip_runtime.h>
#include <math.h>

#define N_NODES 100000
#define N_EDGES 1600000
#define D 64
#define NP 4160      // 64*64+64
#define GI3 12480    // 3*NP
#define GIN 2048     // TOPK*D
#define TOPK 32

// ---- workspace layout (float units) ----
#define OFF_PN     0u          // 64
#define OFF_MISC   64u         // 16 (u32): [0]=cand_count [1]=thr_bin
#define OFF_IDX    80u         // 32 (int)
#define OFF_WSEL   112u        // 32
#define OFF_ZFLAT  144u        // 2048
#define OFF_NEWW   2192u       // 4160
#define OFF_GI     6400u       // 12480
#define OFF_GH     18880u      // 12480
#define OFF_HIST   31360u      // 65536 (u32)
#define OFF_Y      96896u      // 100000
#define OFF_DEG    196896u     // 100000 (u32)
#define OFF_DINV   296896u     // 100000
#define OFF_ROWPTR 396896u     // 100001 (u32)
#define OFF_CURSOR 496898u     // 100000 (u32)
#define OFF_COL    596898u     // 1600000 (int)
#define OFF_CAND   2196898u    // 100000 u64 = 200000 floats (byte off %8==0)
#define OFF_XW     2396898u    // 6400000
#define OFF_H1     8796898u    // 6400000
#define WS_FLOATS  15196898u

__device__ __forceinline__ unsigned fkey(float f) {
    unsigned u = __float_as_uint(f);
    return u ^ ((u & 0x80000000u) ? 0xFFFFFFFFu : 0x80000000u);
}

__global__ void k_zero32(unsigned* __restrict__ p, int n) {
    int i = blockIdx.x * blockDim.x + threadIdx.x;
    if (i < n) p[i] = 0u;
}

__global__ void k_count(const int* __restrict__ dst, unsigned* __restrict__ deg, int ne) {
    int i = blockIdx.x * blockDim.x + threadIdx.x;
    if (i < ne) atomicAdd(&deg[dst[i]], 1u);
}

__global__ void k_dinv(const unsigned* __restrict__ deg, float* __restrict__ dinv, int n) {
    int i = blockIdx.x * blockDim.x + threadIdx.x;
    if (i < n) dinv[i] = rsqrtf((float)(deg[i] + 1u));   // +1 self loop
}

// single-block exclusive scan of deg -> rowptr (and cursor copy); rowptr[n]=total
__global__ void k_scan(const unsigned* __restrict__ deg, unsigned* __restrict__ rowptr,
                       unsigned* __restrict__ cursor, int n) {
    __shared__ unsigned s[1024];
    int t = threadIdx.x;
    int chunk = (n + 1023) / 1024;
    int lo = t * chunk, hi = lo + chunk; if (hi > n) hi = n; if (lo > n) lo = n;
    unsigned sum = 0;
    for (int i = lo; i < hi; ++i) sum += deg[i];
    s[t] = sum; __syncthreads();
    for (int off = 1; off < 1024; off <<= 1) {
        unsigned add = (t >= off) ? s[t - off] : 0u;
        __syncthreads();
        s[t] += add;
        __syncthreads();
    }
    unsigned run = (t == 0) ? 0u : s[t - 1];
    for (int i = lo; i < hi; ++i) { rowptr[i] = run; cursor[i] = run; run += deg[i]; }
    if (t == 1023) rowptr[n] = s[1023];
}

__global__ void k_fill(const int* __restrict__ src, const int* __restrict__ dst,
                       unsigned* __restrict__ cursor, int* __restrict__ col, int ne) {
    int i = blockIdx.x * blockDim.x + threadIdx.x;
    if (i < ne) {
        unsigned pos = atomicAdd(&cursor[dst[i]], 1u);
        col[pos] = src[i];
    }
}

__global__ void k_pnorm(const float* __restrict__ p, float* __restrict__ pn,
                        unsigned* __restrict__ misc) {
    int t = threadIdx.x;  // 64 threads
    float v = p[t];
    float s = v * v;
    for (int o = 32; o; o >>= 1) s += __shfl_down(s, o, 64);
    s = __shfl(s, 0, 64);
    pn[t] = v / (sqrtf(s) + 1e-8f);
    if (t < 16) misc[t] = 0u;
}

// wave per row: y[i] = dot(h[i,:], pn); histogram of top-16 bits of flipped key
__global__ void k_y_hist(const float* __restrict__ h, const float* __restrict__ pn,
                         float* __restrict__ y, unsigned* __restrict__ hist, int n) {
    int wave = (blockIdx.x * blockDim.x + threadIdx.x) >> 6;
    int lane = threadIdx.x & 63;
    int nw = (gridDim.x * blockDim.x) >> 6;
    float p = pn[lane];
    for (int i = wave; i < n; i += nw) {
        float v = h[(size_t)i * D + lane] * p;
        for (int o = 32; o; o >>= 1) v += __shfl_down(v, o, 64);
        if (lane == 0) {
            y[i] = v;
            atomicAdd(&hist[fkey(v) >> 16], 1u);
        }
    }
}

// find threshold bin: count(key16 >= thr) >= 32, count(key16 > thr) < 32
__global__ void k_thresh(const unsigned* __restrict__ hist, unsigned* __restrict__ misc) {
    __shared__ unsigned cs[256];   // chunk suffix sums
    __shared__ unsigned s2[256];
    __shared__ int tstar;
    int t = threadIdx.x;  // 256 threads
    unsigned sum = 0;
    for (int j = 0; j < 256; ++j) sum += hist[t * 256 + j];
    cs[t] = sum; __syncthreads();
    for (int off = 1; off < 256; off <<= 1) {
        unsigned add = (t + off < 256) ? cs[t + off] : 0u;
        __syncthreads();
        cs[t] += add;
        __syncthreads();
    }
    if (cs[t] >= TOPK && (t == 255 || cs[t + 1] < TOPK)) tstar = t;
    __syncthreads();
    int ts = tstar;
    unsigned above = (ts == 255) ? 0u : cs[ts + 1];
    s2[t] = hist[ts * 256 + t]; __syncthreads();
    for (int off = 1; off < 256; off <<= 1) {
        unsigned add = (t + off < 256) ? s2[t + off] : 0u;
        __syncthreads();
        s2[t] += add;
        __syncthreads();
    }
    if (above + s2[t] >= TOPK && (t == 255 || above + s2[t + 1] < TOPK))
        misc[1] = (unsigned)(ts * 256 + t);
}

__global__ void k_compact(const float* __restrict__ y, unsigned* __restrict__ misc,
                          unsigned long long* __restrict__ cand, int n) {
    int i = blockIdx.x * blockDim.x + threadIdx.x;
    if (i >= n) return;
    unsigned thr = misc[1];
    unsigned k = fkey(y[i]);
    if ((k >> 16) >= thr) {
        unsigned pos = atomicAdd(&misc[0], 1u);
        cand[pos] = ((unsigned long long)k << 32) | (unsigned)(0xFFFFFFFFu - (unsigned)i);
    }
}

// select top-32 in exact jax.lax.top_k order (value desc, index asc)
__global__ void k_select(const float* __restrict__ y, const unsigned* __restrict__ misc,
                         unsigned long long* __restrict__ cand,
                         int* __restrict__ idxb, float* __restrict__ wsel) {
    __shared__ unsigned long long red[1024];
    int t = threadIdx.x;  // 1024 threads
    int C = (int)misc[0];
    for (int k = 0; k < TOPK; ++k) {
        unsigned long long m = 0ull;
        for (int j = t; j < C; j += 1024) { unsigned long long c = cand[j]; if (c > m) m = c; }
        red[t] = m; __syncthreads();
        for (int off = 512; off; off >>= 1) {
            if (t < off && red[t + off] > red[t]) red[t] = red[t + off];
            __syncthreads();
        }
        unsigned long long best = red[0];
        for (int j = t; j < C; j += 1024) if (cand[j] == best) cand[j] = 0ull;
        if (t == 0) {
            int idx = (int)(0xFFFFFFFFu - (unsigned)(best & 0xFFFFFFFFull));
            idxb[k] = idx;
            wsel[k] = tanhf(y[idx]);
        }
        __syncthreads();
    }
}

__global__ void k_zflat(const float* __restrict__ h, const int* __restrict__ idxb,
                        const float* __restrict__ wsel, float* __restrict__ z) {
    int t = blockIdx.x * blockDim.x + threadIdx.x;  // 2048
    if (t < GIN) {
        int k = t & 31, d = t >> 5;
        z[t] = h[(size_t)idxb[k] * D + d] * wsel[k];  // z_flat[d*32+k] = Z[k][d]
    }
}

// wave per row: out[r] = dot(W[r,:], vec) + bias[r]; vec = concat(vecA[:lenA], vecB)
__global__ void k_mv(const float* __restrict__ W, const float* __restrict__ bias,
                     const float* __restrict__ vecA, int lenA, const float* __restrict__ vecB,
                     float* __restrict__ out, int rows, int cols) {
    extern __shared__ float v[];
    for (int j = threadIdx.x; j < cols; j += blockDim.x)
        v[j] = (j < lenA) ? vecA[j] : vecB[j - lenA];
    __syncthreads();
    int wave = (blockIdx.x * blockDim.x + threadIdx.x) >> 6;
    int lane = threadIdx.x & 63;
    if (wave >= rows) return;
    const float4* Wr = (const float4*)(W + (size_t)wave * cols);
    int n4 = cols >> 2;
    float acc = 0.f;
    for (int j = lane; j < n4; j += 64) {
        float4 w4 = Wr[j];
        acc += w4.x * v[4 * j] + w4.y * v[4 * j + 1] + w4.z * v[4 * j + 2] + w4.w * v[4 * j + 3];
    }
    for (int o = 32; o; o >>= 1) acc += __shfl_down(acc, o, 64);
    if (lane == 0) out[wave] = acc + bias[wave];
}

__global__ void k_gru(const float* __restrict__ gi, const float* __restrict__ gh,
                      const float* __restrict__ w, const float* __restrict__ b,
                      float* __restrict__ neww) {
    int j = blockIdx.x * blockDim.x + threadIdx.x;
    if (j >= NP) return;
    float r = 1.f / (1.f + expf(-(gi[j] + gh[j])));
    float z = 1.f / (1.f + expf(-(gi[NP + j] + gh[NP + j])));
    float n = tanhf(gi[2 * NP + j] + r * gh[2 * NP + j]);
    float h0 = (j < 4096) ? w[j] : b[j - 4096];
    neww[j] = (1.f - z) * n + z * h0;
}

// xw[i][o] = sum_d h[i][d] * neww[o*64+d]
__global__ void k_xw(const float* __restrict__ h, const float* __restrict__ neww,
                     float* __restrict__ xw, int n) {
    __shared__ float WT[64 * 64];  // WT[d*64+o] = weight[o][d]
    for (int t = threadIdx.x; t < 4096; t += blockDim.x) {
        int o = t >> 6, d = t & 63;
        WT[d * 64 + o] = neww[t];
    }
    __syncthreads();
    int wave = (blockIdx.x * blockDim.x + threadIdx.x) >> 6;
    int lane = threadIdx.x & 63;
    int nw = (gridDim.x * blockDim.x) >> 6;
    for (int i = wave; i < n; i += nw) {
        float hv = h[(size_t)i * D + lane];
        float acc = 0.f;
        #pragma unroll 16
        for (int d = 0; d < 64; ++d) {
            float hd = __shfl(hv, d, 64);
            acc += hd * WT[d * 64 + lane];
        }
        xw[(size_t)i * D + lane] = acc;
    }
}

// wave per node: out[v][o] = bias[o] + dinv[v]*(dinv[v]*xw[v][o] + sum_e dinv[s]*xw[s][o])
__global__ void k_agg(const float* __restrict__ xw, const float* __restrict__ dinv,
                      const unsigned* __restrict__ rowptr, const int* __restrict__ col,
                      const float* __restrict__ neww, float* __restrict__ out,
                      int n, int relu) {
    int wave = (blockIdx.x * blockDim.x + threadIdx.x) >> 6;
    int lane = threadIdx.x & 63;
    int nw = (gridDim.x * blockDim.x) >> 6;
    float bias = neww[4096 + lane];
    for (int v = wave; v < n; v += nw) {
        unsigned p0 = rowptr[v], p1 = rowptr[v + 1];
        float dv = dinv[v];
        float acc = dv * xw[(size_t)v * D + lane];
        for (unsigned base = p0; base < p1; base += 64) {
            int cnt = (int)min(64u, p1 - base);
            int s = 0; float ds = 0.f;
            if (lane < cnt) { s = col[base + lane]; ds = dinv[s]; }
            for (int j = 0; j < cnt; ++j) {
                int sj = __shfl(s, j, 64);
                float dsj = __shfl(ds, j, 64);
                acc += dsj * xw[(size_t)sj * D + lane];
            }
        }
        float r = bias + dv * acc;
        if (relu) r = fmaxf(r, 0.f);
        out[(size_t)v * D + lane] = r;
    }
}

extern "C" void kernel_launch(void* const* d_in, const int* in_sizes, int n_in,
                              void* d_out, int out_size, void* d_ws, size_t ws_size,
                              hipStream_t stream) {
    if (ws_size < (size_t)WS_FLOATS * 4) return;  // workspace too small: fail cleanly

    const float* x = (const float*)d_in[0];
    const int* src = (const int*)d_in[1];
    const int* dst = src + N_EDGES;
    const float* P[2]   = {(const float*)d_in[2],  (const float*)d_in[3]};
    const float* W[2]   = {(const float*)d_in[4],  (const float*)d_in[6]};
    const float* B[2]   = {(const float*)d_in[5],  (const float*)d_in[7]};
    const float* WIH[2] = {(const float*)d_in[8],  (const float*)d_in[12]};
    const float* WHH[2] = {(const float*)d_in[9],  (const float*)d_in[13]};
    const float* BIH[2] = {(const float*)d_in[10], (const float*)d_in[14]};
    const float* BHH[2] = {(const float*)d_in[11], (const float*)d_in[15]};

    float* ws = (float*)d_ws;
    float* pn = ws + OFF_PN;
    unsigned* misc = (unsigned*)(ws + OFF_MISC);
    int* idxb = (int*)(ws + OFF_IDX);
    float* wsel = ws + OFF_WSEL;
    float* zflat = ws + OFF_ZFLAT;
    float* neww = ws + OFF_NEWW;
    float* gi = ws + OFF_GI;
    float* gh = ws + OFF_GH;
    unsigned* hist = (unsigned*)(ws + OFF_HIST);
    float* y = ws + OFF_Y;
    unsigned* deg = (unsigned*)(ws + OFF_DEG);
    float* dinv = ws + OFF_DINV;
    unsigned* rowptr = (unsigned*)(ws + OFF_ROWPTR);
    unsigned* cursor = (unsigned*)(ws + OFF_CURSOR);
    int* col = (int*)(ws + OFF_COL);
    unsigned long long* cand = (unsigned long long*)(ws + OFF_CAND);
    float* xw = ws + OFF_XW;
    float* h1 = ws + OFF_H1;
    float* out = (float*)d_out;

    // ---- CSR build (shared by both layers) ----
    hipLaunchKernelGGL(k_zero32, dim3((N_NODES + 255) / 256), dim3(256), 0, stream, deg, N_NODES);
    hipLaunchKernelGGL(k_count, dim3((N_EDGES + 255) / 256), dim3(256), 0, stream, dst, deg, N_EDGES);
    hipLaunchKernelGGL(k_dinv, dim3((N_NODES + 255) / 256), dim3(256), 0, stream, deg, dinv, N_NODES);
    hipLaunchKernelGGL(k_scan, dim3(1), dim3(1024), 0, stream, deg, rowptr, cursor, N_NODES);
    hipLaunchKernelGGL(k_fill, dim3((N_EDGES + 255) / 256), dim3(256), 0, stream, src, dst, cursor, col, N_EDGES);

    for (int l = 0; l < 2; ++l) {
        const float* h = (l == 0) ? x : h1;
        float* ho = (l == 0) ? h1 : out;
        hipLaunchKernelGGL(k_zero32, dim3(256), dim3(256), 0, stream, hist, 65536);
        hipLaunchKernelGGL(k_pnorm, dim3(1), dim3(64), 0, stream, P[l], pn, misc);
        hipLaunchKernelGGL(k_y_hist, dim3(1024), dim3(256), 0, stream, h, pn, y, hist, N_NODES);
        hipLaunchKernelGGL(k_thresh, dim3(1), dim3(256), 0, stream, hist, misc);
        hipLaunchKernelGGL(k_compact, dim3((N_NODES + 255) / 256), dim3(256), 0, stream, y, misc, cand, N_NODES);
        hipLaunchKernelGGL(k_select, dim3(1), dim3(1024), 0, stream, y, misc, cand, idxb, wsel);
        hipLaunchKernelGGL(k_zflat, dim3(8), dim3(256), 0, stream, h, idxb, wsel, zflat);
        hipLaunchKernelGGL(k_mv, dim3(GI3 / 4), dim3(256), GIN * 4, stream,
                           WIH[l], BIH[l], zflat, GIN, zflat, gi, GI3, GIN);
        hipLaunchKernelGGL(k_mv, dim3(GI3 / 4), dim3(256), NP * 4, stream,
                           WHH[l], BHH[l], W[l], 4096, B[l], gh, GI3, NP);
        hipLaunchKernelGGL(k_gru, dim3((NP + 255) / 256), dim3(256), 0, stream, gi, gh, W[l], B[l], neww);
        hipLaunchKernelGGL(k_xw, dim3(2048), dim3(256), 0, stream, h, neww, xw, N_NODES);
        hipLaunchKernelGGL(k_agg, dim3(4096), dim3(256), 0, stream, xw, dinv, rowptr, col, neww, ho,
                           N_NODES, (l == 0) ? 1 : 0);
    }
}

// Round 2
// 1511.374 us; speedup vs baseline: 1.1763x; 1.1763x over previous
//
#include <hip/hip_runtime.h>
#include <math.h>

#define N_NODES 100000
#define N_EDGES 1600000
#define D 64
#define NP 4160      // 64*64+64
#define GI3 12480    // 3*NP
#define GIN 2048     // TOPK*D
#define TOPK 32
#define SCAN_BLKS 98 // ceil(100000/1024)

// ---- workspace layout (float units) ----
#define OFF_PN     0u          // 64
#define OFF_MISC   64u         // 16 (u32): [0]=cand_count [1]=thr_bin
#define OFF_IDX    80u         // 32 (int)
#define OFF_WSEL   112u        // 32
#define OFF_ZFLAT  144u        // 2048
#define OFF_NEWW   2192u       // 4160
#define OFF_GI     6400u       // 12480
#define OFF_GH     18880u      // 12480
#define OFF_HIST   31360u      // 65536 (u32)
#define OFF_Y      96896u      // 100000
#define OFF_DEG    196896u     // 100000 (u32)
#define OFF_DINV   296896u     // 100000
#define OFF_ROWPTR 396896u     // 100001 (u32)
#define OFF_CURSOR 496898u     // 100000 (u32)
#define OFF_COL    596898u     // 1600000 (int)
#define OFF_CAND   2196898u    // 100000 u64 = 200000 floats (byte off %8==0)
#define OFF_XW     2396898u    // 6400000
#define OFF_H1     8796898u    // 6400000
#define OFF_BSUM   15196898u   // 128 (u32)
#define WS_FLOATS  15197026u

__device__ __forceinline__ unsigned fkey(float f) {
    unsigned u = __float_as_uint(f);
    return u ^ ((u & 0x80000000u) ? 0xFFFFFFFFu : 0x80000000u);
}

__global__ void k_zero32(unsigned* __restrict__ p, int n) {
    int i = blockIdx.x * blockDim.x + threadIdx.x;
    if (i < n) p[i] = 0u;
}

__global__ void k_count(const int* __restrict__ dst, unsigned* __restrict__ deg, int ne) {
    int i = blockIdx.x * blockDim.x + threadIdx.x;
    if (i < ne) atomicAdd(&deg[dst[i]], 1u);
}

__global__ void k_dinv(const unsigned* __restrict__ deg, float* __restrict__ dinv, int n) {
    int i = blockIdx.x * blockDim.x + threadIdx.x;
    if (i < n) dinv[i] = rsqrtf((float)(deg[i] + 1u));   // +1 self loop
}

// ---- hierarchical exclusive scan: deg -> rowptr/cursor ----
// Phase A: per-block sums (256 thr x 4 elem = 1024 elem/block)
__global__ void k_scanA(const unsigned* __restrict__ deg, unsigned* __restrict__ bsum, int n) {
    __shared__ unsigned s[256];
    int t = threadIdx.x;
    int base = blockIdx.x * 1024 + t * 4;
    unsigned v = 0;
    #pragma unroll
    for (int j = 0; j < 4; ++j) { int i = base + j; if (i < n) v += deg[i]; }
    s[t] = v; __syncthreads();
    for (int off = 128; off; off >>= 1) {
        if (t < off) s[t] += s[t + off];
        __syncthreads();
    }
    if (t == 0) bsum[blockIdx.x] = s[0];
}

// Phase B: single small block scans the block sums (exclusive, in place); writes total
__global__ void k_scanB(unsigned* __restrict__ bsum, unsigned* __restrict__ rowptr, int nb, int n) {
    __shared__ unsigned s[128];
    int t = threadIdx.x;  // 128 threads, nb <= 128
    unsigned v = (t < nb) ? bsum[t] : 0u;
    s[t] = v; __syncthreads();
    for (int off = 1; off < 128; off <<= 1) {
        unsigned a = (t >= off) ? s[t - off] : 0u;
        __syncthreads();
        s[t] += a;
        __syncthreads();
    }
    if (t < nb) bsum[t] = s[t] - v;   // exclusive
    if (t == 127) rowptr[n] = s[127]; // grand total
}

// Phase C: block-local exclusive scan + block offset -> rowptr, cursor
__global__ void k_scanC(const unsigned* __restrict__ deg, const unsigned* __restrict__ bsum,
                        unsigned* __restrict__ rowptr, unsigned* __restrict__ cursor, int n) {
    __shared__ unsigned s[256];
    int t = threadIdx.x;
    int base = blockIdx.x * 1024 + t * 4;
    unsigned loc[4]; unsigned v = 0;
    #pragma unroll
    for (int j = 0; j < 4; ++j) { int i = base + j; loc[j] = (i < n) ? deg[i] : 0u; v += loc[j]; }
    s[t] = v; __syncthreads();
    for (int off = 1; off < 256; off <<= 1) {
        unsigned a = (t >= off) ? s[t - off] : 0u;
        __syncthreads();
        s[t] += a;
        __syncthreads();
    }
    unsigned run = bsum[blockIdx.x] + s[t] - v;  // exclusive prefix of this thread's chunk
    #pragma unroll
    for (int j = 0; j < 4; ++j) {
        int i = base + j;
        if (i < n) { rowptr[i] = run; cursor[i] = run; run += loc[j]; }
    }
}

__global__ void k_fill(const int* __restrict__ src, const int* __restrict__ dst,
                       unsigned* __restrict__ cursor, int* __restrict__ col, int ne) {
    int i = blockIdx.x * blockDim.x + threadIdx.x;
    if (i < ne) {
        unsigned pos = atomicAdd(&cursor[dst[i]], 1u);
        col[pos] = src[i];
    }
}

__global__ void k_pnorm(const float* __restrict__ p, float* __restrict__ pn,
                        unsigned* __restrict__ misc) {
    int t = threadIdx.x;  // 64 threads
    float v = p[t];
    float s = v * v;
    for (int o = 32; o; o >>= 1) s += __shfl_down(s, o, 64);
    s = __shfl(s, 0, 64);
    pn[t] = v / (sqrtf(s) + 1e-8f);
    if (t < 16) misc[t] = 0u;
}

// wave per row: y[i] = dot(h[i,:], pn); histogram of top-16 bits of flipped key
__global__ void k_y_hist(const float* __restrict__ h, const float* __restrict__ pn,
                         float* __restrict__ y, unsigned* __restrict__ hist, int n) {
    int wave = (blockIdx.x * blockDim.x + threadIdx.x) >> 6;
    int lane = threadIdx.x & 63;
    int nw = (gridDim.x * blockDim.x) >> 6;
    float p = pn[lane];
    for (int i = wave; i < n; i += nw) {
        float v = h[(size_t)i * D + lane] * p;
        for (int o = 32; o; o >>= 1) v += __shfl_down(v, o, 64);
        if (lane == 0) {
            y[i] = v;
            atomicAdd(&hist[fkey(v) >> 16], 1u);
        }
    }
}

// find threshold bin: count(key16 >= thr) >= 32, count(key16 > thr) < 32
__global__ void k_thresh(const unsigned* __restrict__ hist, unsigned* __restrict__ misc) {
    __shared__ unsigned cs[256];   // chunk suffix sums
    __shared__ unsigned s2[256];
    __shared__ int tstar;
    int t = threadIdx.x;  // 256 threads
    unsigned sum = 0;
    for (int j = 0; j < 256; ++j) sum += hist[t * 256 + j];
    cs[t] = sum; __syncthreads();
    for (int off = 1; off < 256; off <<= 1) {
        unsigned add = (t + off < 256) ? cs[t + off] : 0u;
        __syncthreads();
        cs[t] += add;
        __syncthreads();
    }
    if (cs[t] >= TOPK && (t == 255 || cs[t + 1] < TOPK)) tstar = t;
    __syncthreads();
    int ts = tstar;
    unsigned above = (ts == 255) ? 0u : cs[ts + 1];
    s2[t] = hist[ts * 256 + t]; __syncthreads();
    for (int off = 1; off < 256; off <<= 1) {
        unsigned add = (t + off < 256) ? s2[t + off] : 0u;
        __syncthreads();
        s2[t] += add;
        __syncthreads();
    }
    if (above + s2[t] >= TOPK && (t == 255 || above + s2[t + 1] < TOPK))
        misc[1] = (unsigned)(ts * 256 + t);
}

__global__ void k_compact(const float* __restrict__ y, unsigned* __restrict__ misc,
                          unsigned long long* __restrict__ cand, int n) {
    int i = blockIdx.x * blockDim.x + threadIdx.x;
    if (i >= n) return;
    unsigned thr = misc[1];
    unsigned k = fkey(y[i]);
    if ((k >> 16) >= thr) {
        unsigned pos = atomicAdd(&misc[0], 1u);
        cand[pos] = ((unsigned long long)k << 32) | (unsigned)(0xFFFFFFFFu - (unsigned)i);
    }
}

// select top-32 in exact jax.lax.top_k order (value desc, index asc) — one wave, shuffle max
__global__ void k_select(const float* __restrict__ y, const unsigned* __restrict__ misc,
                         unsigned long long* __restrict__ cand,
                         int* __restrict__ idxb, float* __restrict__ wsel) {
    int t = threadIdx.x;  // 64 threads
    int C = (int)misc[0];
    for (int k = 0; k < TOPK; ++k) {
        unsigned long long m = 0ull;
        for (int j = t; j < C; j += 64) { unsigned long long c = cand[j]; if (c > m) m = c; }
        for (int o = 32; o; o >>= 1) {
            unsigned long long other = __shfl_down(m, o, 64);
            if (other > m) m = other;
        }
        unsigned long long best = __shfl(m, 0, 64);
        for (int j = t; j < C; j += 64) if (cand[j] == best) cand[j] = 0ull;
        if (t == 0) {
            int idx = (int)(0xFFFFFFFFu - (unsigned)(best & 0xFFFFFFFFull));
            idxb[k] = idx;
            wsel[k] = tanhf(y[idx]);
        }
    }
}

__global__ void k_zflat(const float* __restrict__ h, const int* __restrict__ idxb,
                        const float* __restrict__ wsel, float* __restrict__ z) {
    int t = blockIdx.x * blockDim.x + threadIdx.x;  // 2048
    if (t < GIN) {
        int k = t & 31, d = t >> 5;
        z[t] = h[(size_t)idxb[k] * D + d] * wsel[k];  // z_flat[d*32+k] = Z[k][d]
    }
}

// wave per row: out[r] = dot(W[r,:], vec) + bias[r]; vec = concat(vecA[:lenA], vecB)
__global__ void k_mv(const float* __restrict__ W, const float* __restrict__ bias,
                     const float* __restrict__ vecA, int lenA, const float* __restrict__ vecB,
                     float* __restrict__ out, int rows, int cols) {
    extern __shared__ float v[];
    for (int j = threadIdx.x; j < cols; j += blockDim.x)
        v[j] = (j < lenA) ? vecA[j] : vecB[j - lenA];
    __syncthreads();
    int wave = (blockIdx.x * blockDim.x + threadIdx.x) >> 6;
    int lane = threadIdx.x & 63;
    if (wave >= rows) return;
    const float4* Wr = (const float4*)(W + (size_t)wave * cols);
    int n4 = cols >> 2;
    float acc = 0.f;
    for (int j = lane; j < n4; j += 64) {
        float4 w4 = Wr[j];
        acc += w4.x * v[4 * j] + w4.y * v[4 * j + 1] + w4.z * v[4 * j + 2] + w4.w * v[4 * j + 3];
    }
    for (int o = 32; o; o >>= 1) acc += __shfl_down(acc, o, 64);
    if (lane == 0) out[wave] = acc + bias[wave];
}

__global__ void k_gru(const float* __restrict__ gi, const float* __restrict__ gh,
                      const float* __restrict__ w, const float* __restrict__ b,
                      float* __restrict__ neww) {
    int j = blockIdx.x * blockDim.x + threadIdx.x;
    if (j >= NP) return;
    float r = 1.f / (1.f + expf(-(gi[j] + gh[j])));
    float z = 1.f / (1.f + expf(-(gi[NP + j] + gh[NP + j])));
    float n = tanhf(gi[2 * NP + j] + r * gh[2 * NP + j]);
    float h0 = (j < 4096) ? w[j] : b[j - 4096];
    neww[j] = (1.f - z) * n + z * h0;
}

// xw[i][o] = sum_d h[i][d] * neww[o*64+d]
__global__ void k_xw(const float* __restrict__ h, const float* __restrict__ neww,
                     float* __restrict__ xw, int n) {
    __shared__ float WT[64 * 64];  // WT[d*64+o] = weight[o][d]
    for (int t = threadIdx.x; t < 4096; t += blockDim.x) {
        int o = t >> 6, d = t & 63;
        WT[d * 64 + o] = neww[t];
    }
    __syncthreads();
    int wave = (blockIdx.x * blockDim.x + threadIdx.x) >> 6;
    int lane = threadIdx.x & 63;
    int nw = (gridDim.x * blockDim.x) >> 6;
    for (int i = wave; i < n; i += nw) {
        float hv = h[(size_t)i * D + lane];
        float acc = 0.f;
        #pragma unroll 16
        for (int d = 0; d < 64; ++d) {
            float hd = __shfl(hv, d, 64);
            acc += hd * WT[d * 64 + lane];
        }
        xw[(size_t)i * D + lane] = acc;
    }
}

// wave per node: out[v][o] = bias[o] + dinv[v]*(dinv[v]*xw[v][o] + sum_e dinv[s]*xw[s][o])
__global__ void k_agg(const float* __restrict__ xw, const float* __restrict__ dinv,
                      const unsigned* __restrict__ rowptr, const int* __restrict__ col,
                      const float* __restrict__ neww, float* __restrict__ out,
                      int n, int relu) {
    int wave = (blockIdx.x * blockDim.x + threadIdx.x) >> 6;
    int lane = threadIdx.x & 63;
    int nw = (gridDim.x * blockDim.x) >> 6;
    float bias = neww[4096 + lane];
    for (int v = wave; v < n; v += nw) {
        unsigned p0 = rowptr[v], p1 = rowptr[v + 1];
        float dv = dinv[v];
        float acc = dv * xw[(size_t)v * D + lane];
        for (unsigned base = p0; base < p1; base += 64) {
            int cnt = (int)min(64u, p1 - base);
            int s = 0; float ds = 0.f;
            if (lane < cnt) { s = col[base + lane]; ds = dinv[s]; }
            for (int j = 0; j < cnt; ++j) {
                int sj = __shfl(s, j, 64);
                float dsj = __shfl(ds, j, 64);
                acc += dsj * xw[(size_t)sj * D + lane];
            }
        }
        float r = bias + dv * acc;
        if (relu) r = fmaxf(r, 0.f);
        out[(size_t)v * D + lane] = r;
    }
}

extern "C" void kernel_launch(void* const* d_in, const int* in_sizes, int n_in,
                              void* d_out, int out_size, void* d_ws, size_t ws_size,
                              hipStream_t stream) {
    if (ws_size < (size_t)WS_FLOATS * 4) return;  // workspace too small: fail cleanly

    const float* x = (const float*)d_in[0];
    const int* src = (const int*)d_in[1];
    const int* dst = src + N_EDGES;
    const float* P[2]   = {(const float*)d_in[2],  (const float*)d_in[3]};
    const float* W[2]   = {(const float*)d_in[4],  (const float*)d_in[6]};
    const float* B[2]   = {(const float*)d_in[5],  (const float*)d_in[7]};
    const float* WIH[2] = {(const float*)d_in[8],  (const float*)d_in[12]};
    const float* WHH[2] = {(const float*)d_in[9],  (const float*)d_in[13]};
    const float* BIH[2] = {(const float*)d_in[10], (const float*)d_in[14]};
    const float* BHH[2] = {(const float*)d_in[11], (const float*)d_in[15]};

    float* ws = (float*)d_ws;
    float* pn = ws + OFF_PN;
    unsigned* misc = (unsigned*)(ws + OFF_MISC);
    int* idxb = (int*)(ws + OFF_IDX);
    float* wsel = ws + OFF_WSEL;
    float* zflat = ws + OFF_ZFLAT;
    float* neww = ws + OFF_NEWW;
    float* gi = ws + OFF_GI;
    float* gh = ws + OFF_GH;
    unsigned* hist = (unsigned*)(ws + OFF_HIST);
    float* y = ws + OFF_Y;
    unsigned* deg = (unsigned*)(ws + OFF_DEG);
    float* dinv = ws + OFF_DINV;
    unsigned* rowptr = (unsigned*)(ws + OFF_ROWPTR);
    unsigned* cursor = (unsigned*)(ws + OFF_CURSOR);
    int* col = (int*)(ws + OFF_COL);
    unsigned long long* cand = (unsigned long long*)(ws + OFF_CAND);
    float* xw = ws + OFF_XW;
    float* h1 = ws + OFF_H1;
    unsigned* bsum = (unsigned*)(ws + OFF_BSUM);
    float* out = (float*)d_out;

    // ---- CSR build (shared by both layers) ----
    hipLaunchKernelGGL(k_zero32, dim3((N_NODES + 255) / 256), dim3(256), 0, stream, deg, N_NODES);
    hipLaunchKernelGGL(k_count, dim3((N_EDGES + 255) / 256), dim3(256), 0, stream, dst, deg, N_EDGES);
    hipLaunchKernelGGL(k_dinv, dim3((N_NODES + 255) / 256), dim3(256), 0, stream, deg, dinv, N_NODES);
    hipLaunchKernelGGL(k_scanA, dim3(SCAN_BLKS), dim3(256), 0, stream, deg, bsum, N_NODES);
    hipLaunchKernelGGL(k_scanB, dim3(1), dim3(128), 0, stream, bsum, rowptr, SCAN_BLKS, N_NODES);
    hipLaunchKernelGGL(k_scanC, dim3(SCAN_BLKS), dim3(256), 0, stream, deg, bsum, rowptr, cursor, N_NODES);
    hipLaunchKernelGGL(k_fill, dim3((N_EDGES + 255) / 256), dim3(256), 0, stream, src, dst, cursor, col, N_EDGES);

    for (int l = 0; l < 2; ++l) {
        const float* h = (l == 0) ? x : h1;
        float* ho = (l == 0) ? h1 : out;
        hipLaunchKernelGGL(k_zero32, dim3(256), dim3(256), 0, stream, hist, 65536);
        hipLaunchKernelGGL(k_pnorm, dim3(1), dim3(64), 0, stream, P[l], pn, misc);
        hipLaunchKernelGGL(k_y_hist, dim3(1024), dim3(256), 0, stream, h, pn, y, hist, N_NODES);
        hipLaunchKernelGGL(k_thresh, dim3(1), dim3(256), 0, stream, hist, misc);
        hipLaunchKernelGGL(k_compact, dim3((N_NODES + 255) / 256), dim3(256), 0, stream, y, misc, cand, N_NODES);
        hipLaunchKernelGGL(k_select, dim3(1), dim3(64), 0, stream, y, misc, cand, idxb, wsel);
        hipLaunchKernelGGL(k_zflat, dim3(8), dim3(256), 0, stream, h, idxb, wsel, zflat);
        hipLaunchKernelGGL(k_mv, dim3(GI3 / 4), dim3(256), GIN * 4, stream,
                           WIH[l], BIH[l], zflat, GIN, zflat, gi, GI3, GIN);
        hipLaunchKernelGGL(k_mv, dim3(GI3 / 4), dim3(256), NP * 4, stream,
                           WHH[l], BHH[l], W[l], 4096, B[l], gh, GI3, NP);
        hipLaunchKernelGGL(k_gru, dim3((NP + 255) / 256), dim3(256), 0, stream, gi, gh, W[l], B[l], neww);
        hipLaunchKernelGGL(k_xw, dim3(2048), dim3(256), 0, stream, h, neww, xw, N_NODES);
        hipLaunchKernelGGL(k_agg, dim3(4096), dim3(256), 0, stream, xw, dinv, rowptr, col, neww, ho,
                           N_NODES, (l == 0) ? 1 : 0);
    }
}